// Round 22
// baseline (259.015 us; speedup 1.0000x reference)
//
#include <hip/hip_runtime.h>
#include <hip/hip_bf16.h>

#define NN 2560        // nodes
#define NE 163840      // edges
#define NH 4           // heads
#define NC 128         // channels per head
#define NF 512         // NH*NC
#define OUTE 40
#define CSTR 256       // fixed CSR stride per node; deg>CSTR -> overflow list

typedef short bf16x8 __attribute__((ext_vector_type(8)));
typedef float f32x4 __attribute__((ext_vector_type(4)));

__device__ inline ushort f2bf(float f) {
    uint u = __float_as_uint(f);
    uint r = u + 0x7FFF + ((u >> 16) & 1);   // round-to-nearest-even
    return (ushort)(r >> 16);
}
__device__ inline float bflo(uint v) { return __uint_as_float(v << 16); }
__device__ inline float bfhi(uint v) { return __uint_as_float(v & 0xFFFF0000u); }
__device__ inline float bf2f(ushort u) { return __uint_as_float(((uint)u) << 16); }

// ---------------- kernel 1: CSR fill (single-pass) + dote/WfcT/W2T + GEMM1+att
__global__ __launch_bounds__(256) void k_csr_gemm1(const int* __restrict__ ei,
        const float* __restrict__ pos, int* __restrict__ deg,
        int2* __restrict__ csrp, int* __restrict__ ovf_cnt, int4* __restrict__ ovf,
        const float* __restrict__ We1, const float* __restrict__ ae1,
        const float* __restrict__ We2, const float* __restrict__ ae2,
        float* __restrict__ dote,
        const float* __restrict__ Wfc, ushort* __restrict__ WfcT,
        const float* __restrict__ W2, ushort* __restrict__ W2T,
        const float* __restrict__ x, const float* __restrict__ W1,
        const float* __restrict__ atts, const float* __restrict__ attd,
        ushort* __restrict__ hb, float* __restrict__ as_, float* __restrict__ ad_) {
    __shared__ ushort tile[64][72];
    __shared__ float s_x[4][32];
    __shared__ float4 s_red[4][4];     // [wave][node]
    int b = blockIdx.x;
    if (b < 640) {
        int e = b * 256 + threadIdx.x;
        int s = ei[e], d = ei[NE + e];
        float dx = pos[2 * s] - pos[2 * d];
        float dy = pos[2 * s + 1] - pos[2 * d + 1];
        float w = 1.0f / (sqrtf(dx * dx + dy * dy) + 1e-6f);
        int r = atomicAdd(&deg[d], 1);     // slot + degree in one pass
        if (r < CSTR) {
            csrp[(d << 8) + r] = make_int2(s, __float_as_int(w));
        } else {                            // pathological deg > CSTR: exact fallback
            int i = atomicAdd(ovf_cnt, 1);
            ovf[i] = make_int4(d, s, __float_as_int(w), 0);
        }
        return;
    }
    if (b < 642) {
        int t = threadIdx.x;
        const float* W = (b == 641) ? We2 : We1;
        const float* A = (b == 641) ? ae2 : ae1;
        int w = t >> 6, l = t & 63;
        float p = W[w * 128 + l] * A[w * 128 + l] + W[w * 128 + 64 + l] * A[w * 128 + 64 + l];
#pragma unroll
        for (int o = 32; o > 0; o >>= 1) p += __shfl_down(p, o);
        if (l == 0) dote[(b - 640) * 4 + w] = p;
        return;
    }
    if (b < 738) {
        int idx = (b - 642) * 256 + threadIdx.x;    // j*512 + k
        int j = idx >> 9, k = idx & 511;
        WfcT[idx] = (j < OUTE) ? f2bf(Wfc[k * OUTE + j]) : (ushort)0;
        return;
    }
    if (b < 802) {
        int id = b - 738;
        int n0 = (id & 7) * 64, k0 = (id >> 3) * 64;
        int t = threadIdx.x;
        int r = t >> 2, cseg = (t & 3) * 16;
#pragma unroll
        for (int c = 0; c < 16; c += 4) {
            float4 v = *(const float4*)&W2[(k0 + r) * 512 + n0 + cseg + c];
            tile[cseg + c + 0][r] = f2bf(v.x);
            tile[cseg + c + 1][r] = f2bf(v.y);
            tile[cseg + c + 2][r] = f2bf(v.z);
            tile[cseg + c + 3][r] = f2bf(v.w);
        }
        __syncthreads();
        *(uint4*)&W2T[(n0 + r) * 512 + k0 + cseg]     = *(uint4*)&tile[r][cseg];
        *(uint4*)&W2T[(n0 + r) * 512 + k0 + cseg + 8] = *(uint4*)&tile[r][cseg + 8];
        return;
    }
    int n0 = (b - 802) * 4, t = threadIdx.x;
    if (t < 128) s_x[t >> 5][t & 31] = x[n0 * 32 + t];
    __syncthreads();
    float a0[4] = {0.f, 0.f, 0.f, 0.f}, a1[4] = {0.f, 0.f, 0.f, 0.f};
#pragma unroll
    for (int k = 0; k < 32; k++) {
        float w0 = W1[k * 512 + t];
        float w1 = W1[k * 512 + t + 256];
#pragma unroll
        for (int nn = 0; nn < 4; nn++) {
            a0[nn] += s_x[nn][k] * w0;
            a1[nn] += s_x[nn][k] * w1;
        }
    }
    float sa0 = atts[t], sa1 = atts[t + 256];
    float da0 = attd[t], da1 = attd[t + 256];
    int w = t >> 6, lane = t & 63;
#pragma unroll
    for (int nn = 0; nn < 4; nn++) {
        hb[(n0 + nn) * 512 + t] = f2bf(a0[nn]);
        hb[(n0 + nn) * 512 + t + 256] = f2bf(a1[nn]);
        float ps0 = a0[nn] * sa0, pd0 = a0[nn] * da0;
        float ps1 = a1[nn] * sa1, pd1 = a1[nn] * da1;
#pragma unroll
        for (int o = 32; o > 0; o >>= 1) {
            ps0 += __shfl_xor(ps0, o); pd0 += __shfl_xor(pd0, o);
            ps1 += __shfl_xor(ps1, o); pd1 += __shfl_xor(pd1, o);
        }
        if (lane == 0) s_red[w][nn] = make_float4(ps0, pd0, ps1, pd1);
    }
    __syncthreads();
    if (t < 4) {
        int nn = t, n = n0 + nn;
        float4 r0 = s_red[0][nn], r1 = s_red[1][nn], r2 = s_red[2][nn], r3 = s_red[3][nn];
        as_[n * 4 + 0] = r0.x + r1.x; as_[n * 4 + 1] = r2.x + r3.x;
        as_[n * 4 + 2] = r0.z + r1.z; as_[n * 4 + 3] = r2.z + r3.z;
        ad_[n * 4 + 0] = r0.y + r1.y; ad_[n * 4 + 1] = r2.y + r3.y;
        ad_[n * 4 + 2] = r0.w + r1.w; ad_[n * 4 + 3] = r2.w + r3.w;
    }
}

// ---------------- kernel 2: softmax+agg, WAVE = NODE ----------------------
// R22: one wave per node (was head-pair): same per-wave serial depth, but
// halved wave count -> halved csrp/logit/shfl instruction volume. Lane owns
// 8 channels (uint4 = 1KB/wave/edge). All 4 heads' softmax in registers.
__global__ __launch_bounds__(256) void k_edge_agg(const int* __restrict__ deg_,
        const int2* __restrict__ csrp, const int* __restrict__ ovf_cnt,
        const int4* __restrict__ ovf, const float* __restrict__ as_,
        const float* __restrict__ ad_, const float* __restrict__ dote,
        const ushort* __restrict__ hb, const float* __restrict__ bias,
        ushort* __restrict__ outb) {
    int w = threadIdx.x >> 6, lane = threadIdx.x & 63;
    int n = blockIdx.x * 4 + w;
    int beg = n << 8;
    int degn = deg_[n];
    int dmain = min(degn, CSTR);
    float4 adv = *(const float4*)&ad_[n * 4];
    float4 dt = *(const float4*)&dote[0];
    // ---- phase A: softmax for all 4 heads in registers ----
    float4 La = make_float4(-1e30f, -1e30f, -1e30f, -1e30f), Lb = La;
    int off0 = 0, off1 = 0;
    if (lane < dmain) {
        int2 p = csrp[beg + lane];
        off0 = p.x * NF;
        float4 a = *(const float4*)&as_[p.x * 4];
        float ww = __int_as_float(p.y);
        float v;
        v = a.x + adv.x + ww * dt.x; La.x = v > 0.f ? v : 0.2f * v;
        v = a.y + adv.y + ww * dt.y; La.y = v > 0.f ? v : 0.2f * v;
        v = a.z + adv.z + ww * dt.z; La.z = v > 0.f ? v : 0.2f * v;
        v = a.w + adv.w + ww * dt.w; La.w = v > 0.f ? v : 0.2f * v;
    }
    if (lane + 64 < dmain) {
        int2 p = csrp[beg + lane + 64];
        off1 = p.x * NF;
        float4 a = *(const float4*)&as_[p.x * 4];
        float ww = __int_as_float(p.y);
        float v;
        v = a.x + adv.x + ww * dt.x; Lb.x = v > 0.f ? v : 0.2f * v;
        v = a.y + adv.y + ww * dt.y; Lb.y = v > 0.f ? v : 0.2f * v;
        v = a.z + adv.z + ww * dt.z; Lb.z = v > 0.f ? v : 0.2f * v;
        v = a.w + adv.w + ww * dt.w; Lb.w = v > 0.f ? v : 0.2f * v;
    }
    float4 mx;
    mx.x = fmaxf(La.x, Lb.x); mx.y = fmaxf(La.y, Lb.y);
    mx.z = fmaxf(La.z, Lb.z); mx.w = fmaxf(La.w, Lb.w);
    for (int e = 128 + lane; e < dmain; e += 64) {        // cold: deg > 128
        int2 p = csrp[beg + e];
        float4 a = *(const float4*)&as_[p.x * 4];
        float ww = __int_as_float(p.y);
        float v;
        v = a.x + adv.x + ww * dt.x; v = v > 0.f ? v : 0.2f * v; mx.x = fmaxf(mx.x, v);
        v = a.y + adv.y + ww * dt.y; v = v > 0.f ? v : 0.2f * v; mx.y = fmaxf(mx.y, v);
        v = a.z + adv.z + ww * dt.z; v = v > 0.f ? v : 0.2f * v; mx.z = fmaxf(mx.z, v);
        v = a.w + adv.w + ww * dt.w; v = v > 0.f ? v : 0.2f * v; mx.w = fmaxf(mx.w, v);
    }
    if (degn > CSTR) {                                    // pathological overflow
        int oc = *ovf_cnt;
        for (int i = lane; i < oc; i += 64) {
            int4 o = ovf[i];
            if (o.x == n) {
                float4 a = *(const float4*)&as_[o.y * 4];
                float ww = __int_as_float(o.z);
                float v;
                v = a.x + adv.x + ww * dt.x; v = v > 0.f ? v : 0.2f * v; mx.x = fmaxf(mx.x, v);
                v = a.y + adv.y + ww * dt.y; v = v > 0.f ? v : 0.2f * v; mx.y = fmaxf(mx.y, v);
                v = a.z + adv.z + ww * dt.z; v = v > 0.f ? v : 0.2f * v; mx.z = fmaxf(mx.z, v);
                v = a.w + adv.w + ww * dt.w; v = v > 0.f ? v : 0.2f * v; mx.w = fmaxf(mx.w, v);
            }
        }
    }
#pragma unroll
    for (int o = 32; o > 0; o >>= 1) {
        mx.x = fmaxf(mx.x, __shfl_xor(mx.x, o)); mx.y = fmaxf(mx.y, __shfl_xor(mx.y, o));
        mx.z = fmaxf(mx.z, __shfl_xor(mx.z, o)); mx.w = fmaxf(mx.w, __shfl_xor(mx.w, o));
    }
    float4 Aa, Ab;
    Aa.x = __expf(La.x - mx.x); Aa.y = __expf(La.y - mx.y);
    Aa.z = __expf(La.z - mx.z); Aa.w = __expf(La.w - mx.w);
    Ab.x = __expf(Lb.x - mx.x); Ab.y = __expf(Lb.y - mx.y);
    Ab.z = __expf(Lb.z - mx.z); Ab.w = __expf(Lb.w - mx.w);
    float4 ss;
    ss.x = Aa.x + Ab.x; ss.y = Aa.y + Ab.y; ss.z = Aa.z + Ab.z; ss.w = Aa.w + Ab.w;
    for (int e = 128 + lane; e < dmain; e += 64) {        // cold recompute
        int2 p = csrp[beg + e];
        float4 a = *(const float4*)&as_[p.x * 4];
        float ww = __int_as_float(p.y);
        float v;
        v = a.x + adv.x + ww * dt.x; v = v > 0.f ? v : 0.2f * v; ss.x += __expf(v - mx.x);
        v = a.y + adv.y + ww * dt.y; v = v > 0.f ? v : 0.2f * v; ss.y += __expf(v - mx.y);
        v = a.z + adv.z + ww * dt.z; v = v > 0.f ? v : 0.2f * v; ss.z += __expf(v - mx.z);
        v = a.w + adv.w + ww * dt.w; v = v > 0.f ? v : 0.2f * v; ss.w += __expf(v - mx.w);
    }
    if (degn > CSTR) {
        int oc = *ovf_cnt;
        for (int i = lane; i < oc; i += 64) {
            int4 o = ovf[i];
            if (o.x == n) {
                float4 a = *(const float4*)&as_[o.y * 4];
                float ww = __int_as_float(o.z);
                float v;
                v = a.x + adv.x + ww * dt.x; v = v > 0.f ? v : 0.2f * v; ss.x += __expf(v - mx.x);
                v = a.y + adv.y + ww * dt.y; v = v > 0.f ? v : 0.2f * v; ss.y += __expf(v - mx.y);
                v = a.z + adv.z + ww * dt.z; v = v > 0.f ? v : 0.2f * v; ss.z += __expf(v - mx.z);
                v = a.w + adv.w + ww * dt.w; v = v > 0.f ? v : 0.2f * v; ss.w += __expf(v - mx.w);
            }
        }
    }
#pragma unroll
    for (int o = 32; o > 0; o >>= 1) {
        ss.x += __shfl_xor(ss.x, o); ss.y += __shfl_xor(ss.y, o);
        ss.z += __shfl_xor(ss.z, o); ss.w += __shfl_xor(ss.w, o);
    }
    // ---- phase B: lane owns channels 8*lane..8*lane+7 (head = lane>>4) ----
    int hd = lane >> 4;
    float inv = 1.f / (((const float*)&ss)[hd] + 1e-16f);
    float mxh = ((const float*)&mx)[hd];
    const ushort* hbase = hb + 8 * lane;
    float acc[8] = {0.f, 0.f, 0.f, 0.f, 0.f, 0.f, 0.f, 0.f};
    int m0 = min(dmain, 64);
#pragma unroll 16
    for (int e = 0; e < m0; e++) {
        float a0b = __shfl(Aa.x, e), a1b = __shfl(Aa.y, e);
        float a2b = __shfl(Aa.z, e), a3b = __shfl(Aa.w, e);
        float a = hd == 0 ? a0b : hd == 1 ? a1b : hd == 2 ? a2b : a3b;
        int o = __shfl(off0, e);
        uint4 v = *(const uint4*)(hbase + o);             // 1KB/wave
        acc[0] += a * bflo(v.x); acc[1] += a * bfhi(v.x);
        acc[2] += a * bflo(v.y); acc[3] += a * bfhi(v.y);
        acc[4] += a * bflo(v.z); acc[5] += a * bfhi(v.z);
        acc[6] += a * bflo(v.w); acc[7] += a * bfhi(v.w);
    }
    int m1 = min(dmain, 128);
#pragma unroll 16
    for (int e = 64; e < m1; e++) {
        float a0b = __shfl(Ab.x, e - 64), a1b = __shfl(Ab.y, e - 64);
        float a2b = __shfl(Ab.z, e - 64), a3b = __shfl(Ab.w, e - 64);
        float a = hd == 0 ? a0b : hd == 1 ? a1b : hd == 2 ? a2b : a3b;
        int o = __shfl(off1, e - 64);
        uint4 v = *(const uint4*)(hbase + o);
        acc[0] += a * bflo(v.x); acc[1] += a * bfhi(v.x);
        acc[2] += a * bflo(v.y); acc[3] += a * bfhi(v.y);
        acc[4] += a * bflo(v.z); acc[5] += a * bfhi(v.z);
        acc[6] += a * bflo(v.w); acc[7] += a * bfhi(v.w);
    }
    for (int e = 128; e < dmain; e++) {                   // cold: deg > 128
        int2 p = csrp[beg + e];
        float4 a4 = *(const float4*)&as_[p.x * 4];
        float ww = __int_as_float(p.y);
        float v = ((const float*)&a4)[hd] + ((const float*)&adv)[hd]
                  + ww * ((const float*)&dt)[hd];
        v = v > 0.f ? v : 0.2f * v;
        float a = __expf(v - mxh);
        uint4 vv = *(const uint4*)(hbase + p.x * NF);
        acc[0] += a * bflo(vv.x); acc[1] += a * bfhi(vv.x);
        acc[2] += a * bflo(vv.y); acc[3] += a * bfhi(vv.y);
        acc[4] += a * bflo(vv.z); acc[5] += a * bfhi(vv.z);
        acc[6] += a * bflo(vv.w); acc[7] += a * bfhi(vv.w);
    }
    if (degn > CSTR) {                                    // pathological overflow
        int oc = *ovf_cnt;
        for (int i = 0; i < oc; i++) {
            int4 o = ovf[i];
            if (o.x == n) {
                float4 a4 = *(const float4*)&as_[o.y * 4];
                float ww = __int_as_float(o.z);
                float v = ((const float*)&a4)[hd] + ((const float*)&adv)[hd]
                          + ww * ((const float*)&dt)[hd];
                v = v > 0.f ? v : 0.2f * v;
                float a = __expf(v - mxh);
                uint4 vv = *(const uint4*)(hbase + o.y * NF);
                acc[0] += a * bflo(vv.x); acc[1] += a * bfhi(vv.x);
                acc[2] += a * bflo(vv.y); acc[3] += a * bfhi(vv.y);
                acc[4] += a * bflo(vv.z); acc[5] += a * bfhi(vv.z);
                acc[6] += a * bflo(vv.w); acc[7] += a * bfhi(vv.w);
            }
        }
    }
    int ch = 8 * lane;
    float4 b0 = *(const float4*)&bias[ch];
    float4 b1 = *(const float4*)&bias[ch + 4];
    ushort4 o0, o1;
    o0.x = f2bf(acc[0] * inv + b0.x); o0.y = f2bf(acc[1] * inv + b0.y);
    o0.z = f2bf(acc[2] * inv + b0.z); o0.w = f2bf(acc[3] * inv + b0.w);
    o1.x = f2bf(acc[4] * inv + b1.x); o1.y = f2bf(acc[5] * inv + b1.y);
    o1.z = f2bf(acc[6] * inv + b1.z); o1.w = f2bf(acc[7] * inv + b1.w);
    *(ushort4*)&outb[n * NF + ch]     = o0;
    *(ushort4*)&outb[n * NF + ch + 4] = o1;
}

// ---------------- kernel 3: BN stats from bf16 (160 blocks) ---------------
__global__ void k_bnstats(const ushort* __restrict__ x, float* __restrict__ stats) {
    int t = threadIdx.x;
    int r0 = blockIdx.x * 16;
    float s = 0.f, s2 = 0.f;
    for (int r = r0; r < r0 + 16; r++) {
        float v = bf2f(x[r * NF + t]);
        s += v; s2 += v * v;
    }
    atomicAdd(&stats[t], s);
    atomicAdd(&stats[NF + t], s2);
}

// ---------------- kernel 4: GEMM2 MFMA + inline BN1+relu + node-att -------
// 64x128 tiles -> 160 blocks; A operand bf16 (t1b).
__global__ __launch_bounds__(256) void k_gemm2_bn_att(const ushort* __restrict__ Ab,
        const float* __restrict__ stats, const float* __restrict__ g,
        const float* __restrict__ bb, const ushort* __restrict__ BT,
        const float* __restrict__ atts, const float* __restrict__ attd,
        ushort* __restrict__ Cb, float* __restrict__ as_, float* __restrict__ ad_) {
    __shared__ ushort As[64][40];    // [m][k], +8 pad
    __shared__ ushort Bs[128][40];   // [n][k], +8 pad
    __shared__ float s_scale[512], s_shift[512];
    __shared__ float s_ps[2][64], s_pd[2][64];
    int t = threadIdx.x;
    const float invn = 1.0f / (float)NN;
    {
        int j = t;
#pragma unroll
        for (int rep = 0; rep < 2; rep++, j += 256) {
            float mu = stats[j] * invn;
            float var = stats[NF + j] * invn - mu * mu;
            float sc = rsqrtf(var + 1e-5f) * g[j];
            s_scale[j] = sc;
            s_shift[j] = bb[j] - mu * sc;
        }
    }
    int head = blockIdx.x;
    int rowBase = blockIdx.y * 64, colBase = head * 128;
    int w = t >> 6, lane = t & 63;
    int wm = (w >> 1) * 32, wn = (w & 1) * 64;
    int lm = lane & 15, q = lane >> 4;
    f32x4 acc[2][4] = {};
    int sr2 = t >> 2, sk = (t & 3) * 8;
    for (int k0 = 0; k0 < 512; k0 += 32) {
        __syncthreads();
        int jb = k0 + sk;
        float sc[8], sh[8];
#pragma unroll
        for (int c = 0; c < 8; c++) { sc[c] = s_scale[jb + c]; sh[c] = s_shift[jb + c]; }
        uint4 a8 = *(const uint4*)&Ab[(rowBase + sr2) * 512 + jb];   // 8 bf16
        uint4 b0 = *(const uint4*)&BT[(colBase + sr2) * 512 + jb];
        uint4 b1 = *(const uint4*)&BT[(colBase + 64 + sr2) * 512 + jb];
        ushort pa0[8];
        float av[8];
        av[0] = bflo(a8.x); av[1] = bfhi(a8.x); av[2] = bflo(a8.y); av[3] = bfhi(a8.y);
        av[4] = bflo(a8.z); av[5] = bfhi(a8.z); av[6] = bflo(a8.w); av[7] = bfhi(a8.w);
#pragma unroll
        for (int c = 0; c < 8; c++)
            pa0[c] = f2bf(fmaxf(av[c] * sc[c] + sh[c], 0.f));
        *(uint4*)&As[sr2][sk]      = *(uint4*)pa0;
        *(uint4*)&Bs[sr2][sk]      = b0;
        *(uint4*)&Bs[64 + sr2][sk] = b1;
        __syncthreads();
        bf16x8 af[2], bf[4];
#pragma unroll
        for (int i = 0; i < 2; i++) af[i] = *(const bf16x8*)&As[wm + i * 16 + lm][q * 8];
#pragma unroll
        for (int j = 0; j < 4; j++) bf[j] = *(const bf16x8*)&Bs[wn + j * 16 + lm][q * 8];
#pragma unroll
        for (int i = 0; i < 2; i++)
#pragma unroll
            for (int j = 0; j < 4; j++)
                acc[i][j] = __builtin_amdgcn_mfma_f32_16x16x32_bf16(af[i], bf[j], acc[i][j], 0, 0, 0);
    }
    // C store (bf16)
#pragma unroll
    for (int i = 0; i < 2; i++) {
        int row = rowBase + wm + i * 16 + q * 4;
#pragma unroll
        for (int j = 0; j < 4; j++) {
            int col = colBase + wn + j * 16 + lm;
#pragma unroll
            for (int r = 0; r < 4; r++)
                Cb[(row + r) * 512 + col] = f2bf(acc[i][j][r]);
        }
    }
    // node-att epilogue: head dot for this block's 64 rows
    float sa[4], da[4];
#pragma unroll
    for (int j = 0; j < 4; j++) {
        int col = colBase + wn + j * 16 + lm;
        sa[j] = atts[col]; da[j] = attd[col];
    }
#pragma unroll
    for (int i = 0; i < 2; i++) {
#pragma unroll
        for (int r = 0; r < 4; r++) {
            float ps = 0.f, pd = 0.f;
#pragma unroll
            for (int j = 0; j < 4; j++) {
                float c = acc[i][j][r];
                ps += c * sa[j]; pd += c * da[j];
            }
#pragma unroll
            for (int o = 1; o < 16; o <<= 1) { ps += __shfl_xor(ps, o); pd += __shfl_xor(pd, o); }
            if (lm == 0) {
                int row = wm + i * 16 + q * 4 + r;
                s_ps[w & 1][row] = ps; s_pd[w & 1][row] = pd;
            }
        }
    }
    __syncthreads();
    if (t < 64) {
        as_[(rowBase + t) * 4 + head] = s_ps[0][t] + s_ps[1][t];
    } else if (t < 128) {
        int row = t - 64;
        ad_[(rowBase + row) * 4 + head] = s_pd[0][row] + s_pd[1][row];
    }
}

// ---------------- kernel 5: FC MFMA + inline BN2+relu + mask + adj --------
__global__ __launch_bounds__(64) void k_fc_bn(const ushort* __restrict__ e2b,
        const float* __restrict__ stats, const float* __restrict__ g,
        const float* __restrict__ bb, const ushort* __restrict__ WfcT,
        const float* __restrict__ bfc, const int* __restrict__ mask,
        const float* __restrict__ adj, float* __restrict__ out) {
    __shared__ float s_scale[512], s_shift[512];
    int lane = threadIdx.x;
    const float invn = 1.0f / (float)NN;
    for (int j = lane; j < 512; j += 64) {
        float mu = stats[j] * invn;
        float var = stats[NF + j] * invn - mu * mu;
        float sc = rsqrtf(var + 1e-5f) * g[j];
        s_scale[j] = sc;
        s_shift[j] = bb[j] - mu * sc;
    }
    __syncthreads();
    int r0 = blockIdx.x * 16;
    int lm = lane & 15, q = lane >> 4;
    f32x4 acc[3] = {};
#pragma unroll
    for (int k0 = 0; k0 < 512; k0 += 32) {
        int jb = k0 + q * 8;
        uint4 a8 = *(const uint4*)&e2b[(r0 + lm) * 512 + jb];
        float av[8];
        av[0] = bflo(a8.x); av[1] = bfhi(a8.x); av[2] = bflo(a8.y); av[3] = bfhi(a8.y);
        av[4] = bflo(a8.z); av[5] = bfhi(a8.z); av[6] = bflo(a8.w); av[7] = bfhi(a8.w);
        ushort pa[8];
#pragma unroll
        for (int c = 0; c < 8; c++)
            pa[c] = f2bf(fmaxf(av[c] * s_scale[jb + c] + s_shift[jb + c], 0.f));
        bf16x8 af = *(const bf16x8*)pa;
#pragma unroll
        for (int jt = 0; jt < 3; jt++) {
            bf16x8 bf = *(const bf16x8*)&WfcT[(jt * 16 + lm) * 512 + k0 + q * 8];
            acc[jt] = __builtin_amdgcn_mfma_f32_16x16x32_bf16(af, bf, acc[jt], 0, 0, 0);
        }
    }
#pragma unroll
    for (int jt = 0; jt < 3; jt++) {
        int col = jt * 16 + lm;
        if (col < OUTE) {
#pragma unroll
            for (int r = 0; r < 4; r++) {
                int n = r0 + q * 4 + r;
                float v = acc[jt][r] + bfc[col];
                v = mask[n] ? v : 0.f;
                out[n * OUTE + col] = v + adj[n * OUTE + col];
            }
        }
    }
}

// ---------------- host side ----------------------------------------------
extern "C" void kernel_launch(void* const* d_in, const int* in_sizes, int n_in,
                              void* d_out, int out_size, void* d_ws, size_t ws_size,
                              hipStream_t stream) {
    const float* x       = (const float*)d_in[0];
    const int*   ei      = (const int*)d_in[1];
    const float* pos     = (const float*)d_in[2];
    const int*   mask    = (const int*)d_in[3];
    const float* adj     = (const float*)d_in[4];
    const float* W1      = (const float*)d_in[5];
    const float* atts1   = (const float*)d_in[6];
    const float* attd1   = (const float*)d_in[7];
    const float* We1     = (const float*)d_in[8];
    const float* atte1   = (const float*)d_in[9];
    const float* bias1   = (const float*)d_in[10];
    const float* g1      = (const float*)d_in[11];
    const float* be1     = (const float*)d_in[12];
    const float* W2      = (const float*)d_in[13];
    const float* atts2   = (const float*)d_in[14];
    const float* attd2   = (const float*)d_in[15];
    const float* We2     = (const float*)d_in[16];
    const float* atte2   = (const float*)d_in[17];
    const float* bias2   = (const float*)d_in[18];
    const float* g2      = (const float*)d_in[19];
    const float* be2     = (const float*)d_in[20];
    const float* Wfc     = (const float*)d_in[21];
    const float* bfc     = (const float*)d_in[22];
    float* out = (float*)d_out;

    // workspace layout (float-element offsets; 16B-aligned blocks)
    char* ws = (char*)d_ws;
    int*    deg     = (int*)(ws);                       // 2560
    int*    ovf_cnt = (int*)(ws + 2560 * 4);            // 1 (pad 16)
    float*  stats   = (float*)(ws + 5120 * 4);          // 2048 (L1:1024, L2:1024)
    // ---- zero region = first 7168 elements ----
    float*  dote    = (float*)(ws + 7168 * 4);          // 8 (pad 16)
    int2*   csrp    = (int2*)(ws + 7184 * 4);           // 2560*256 int2 = 1310720 ints
    int4*   ovf     = (int4*)(ws + 1317904 * 4);        // 163840 int4 = 655360 ints
    float*  as_     = (float*)(ws + 1973264 * 4);       // 10240
    float*  ad_     = (float*)(ws + 1983504 * 4);       // 10240
    ushort* t1b     = (ushort*)(ws + 1993744 * 4);      // 1310720 bf16 = 655360 ints
    ushort* hb      = (ushort*)(ws + 2649104 * 4);      // 1310720 bf16 = 655360 ints
    ushort* W2T     = (ushort*)(ws + 3304464 * 4);      // 262144 bf16 = 131072 ints
    ushort* WfcT    = (ushort*)(ws + 3435536 * 4);      // 24576 bf16 = 12288 ints
    // total ~3.45M ints = ~13.8 MB

    hipMemsetAsync(d_ws, 0, 7168 * 4, stream);

    // CSR fill (single-pass) + weight prep + GEMM1+att (4 nodes/block)
    k_csr_gemm1<<<802 + NN / 4, 256, 0, stream>>>(ei, pos, deg, csrp, ovf_cnt, ovf,
                                                  We1, atte1, We2, atte2, dote,
                                                  Wfc, WfcT, W2, W2T,
                                                  x, W1, atts1, attd1, hb, as_, ad_);

    // ---- layer 1 ----
    k_edge_agg<<<NN / 4, 256, 0, stream>>>(deg, csrp, ovf_cnt, ovf, as_, ad_,
                                           dote, hb, bias1, t1b);
    k_bnstats<<<NN / 16, 512, 0, stream>>>(t1b, stats);

    // ---- layer 2 (BN1 inline in GEMM2 A-staging; node-att in epilogue) ----
    k_gemm2_bn_att<<<dim3(4, NN / 64), 256, 0, stream>>>(t1b, stats, g1, be1, W2T,
                                                         atts2, attd2, hb, as_, ad_);
    k_edge_agg<<<NN / 4, 256, 0, stream>>>(deg, csrp, ovf_cnt, ovf, as_, ad_,
                                           dote + 4, hb, bias2, t1b);
    k_bnstats<<<NN / 16, 512, 0, stream>>>(t1b, stats + 1024);

    // ---- head (BN2 inline in FC A-fragment load) ----
    k_fc_bn<<<NN / 16, 64, 0, stream>>>(t1b, stats + 1024, g2, be2, WfcT, bfc, mask, adj, out);
}